// Round 1
// baseline (269.237 us; speedup 1.0000x reference)
//
#include <hip/hip_runtime.h>

typedef unsigned short u16;
typedef unsigned int u32;
typedef __attribute__((ext_vector_type(8))) short bf16x8;
typedef __attribute__((ext_vector_type(4))) short bf16x4;
typedef __attribute__((ext_vector_type(4))) float f32x4;

__device__ __forceinline__ float b2f(u16 b){ u32 u = ((u32)b)<<16; float f; __builtin_memcpy(&f,&u,4); return f; }
__device__ __forceinline__ u16 f2b(float f){ u32 u; __builtin_memcpy(&u,&f,4); u32 r = (u + 0x7fffu + ((u>>16)&1u)) >> 16; return (u16)r; }

// ---------------- convert f32 -> bf16 ----------------
__global__ __launch_bounds__(256) void convert_bf16_k(const float* __restrict__ in, u16* __restrict__ out, int n){
  int i = (blockIdx.x*256 + threadIdx.x)*4;
  if (i + 3 < n){
    float4 v = *(const float4*)(in + i);
    bf16x4 o;
    o[0]=(short)f2b(v.x); o[1]=(short)f2b(v.y); o[2]=(short)f2b(v.z); o[3]=(short)f2b(v.w);
    *(bf16x4*)(out + i) = o;
  } else {
    for (; i<n; ++i) out[i]=f2b(in[i]);
  }
}

// ---------------- transpose f32 [R][C] -> bf16 [C][R] ----------------
__global__ __launch_bounds__(256) void transpose_f32_bf16_k(const float* __restrict__ in, u16* __restrict__ out, int R, int C){
  __shared__ float tile[32][33];
  int tx = threadIdx.x & 31, ty = threadIdx.x >> 5; // ty 0..7
  int c0 = blockIdx.x*32, r0 = blockIdx.y*32;
  #pragma unroll
  for (int k=0;k<4;++k){
    int r = r0 + ty + k*8, c = c0 + tx;
    if (r < R && c < C) tile[ty+k*8][tx] = in[(size_t)r*C + c];
  }
  __syncthreads();
  #pragma unroll
  for (int k=0;k<4;++k){
    int c = c0 + ty + k*8, r = r0 + tx;
    if (r < R && c < C) out[(size_t)c*R + r] = f2b(tile[tx][ty+k*8]);
  }
}

// ---------------- degree / CSR ----------------
__global__ __launch_bounds__(256) void deg_init_k(int* __restrict__ deg, int n){
  int i = blockIdx.x*256 + threadIdx.x;
  if (i < n) deg[i] = 1;  // self-loop
}
__global__ __launch_bounds__(256) void deg_count_k(const int* __restrict__ dst, int* __restrict__ deg, int E){
  int e = blockIdx.x*256 + threadIdx.x;
  if (e < E) atomicAdd(&deg[dst[e]], 1);
}
// single block, 256 threads, 4096 nodes (16 per thread)
__global__ __launch_bounds__(256) void scan_k(const int* __restrict__ deg, int* __restrict__ row_ptr,
                                              int* __restrict__ cursor, float* __restrict__ dinv){
  __shared__ int lds[256];
  int t = threadIdx.x;
  int base = t*16;
  int cnt[16]; int s = 0;
  #pragma unroll
  for (int k=0;k<16;++k){
    int d = deg[base+k];
    cnt[k] = d - 1;
    s += d - 1;
    dinv[base+k] = 1.0f / sqrtf((float)d);
  }
  lds[t] = s; __syncthreads();
  for (int o=1;o<256;o<<=1){
    int v = (t>=o) ? lds[t-o] : 0;
    __syncthreads();
    lds[t] += v;
    __syncthreads();
  }
  int run = lds[t] - s;
  #pragma unroll
  for (int k=0;k<16;++k){ row_ptr[base+k] = run; cursor[base+k] = run; run += cnt[k]; }
  if (t == 255) row_ptr[4096] = run;
}
__global__ __launch_bounds__(256) void scatter_k(const int* __restrict__ src, const int* __restrict__ dst,
                                                 int* __restrict__ cursor, int* __restrict__ srcl, int E){
  int e = blockIdx.x*256 + threadIdx.x;
  if (e < E){
    int d = dst[e];
    int pos = atomicAdd(&cursor[d], 1);
    srcl[pos] = src[e];
  }
}

// ---------------- GCN aggregation: out[i] = relu(sum_{e:dst=i} H[src]*dinv[s]*dinv[i] + H[i]*dinv[i]^2 + bias) ----------------
__global__ __launch_bounds__(128) void aggregate_k(const u16* __restrict__ H, const float* __restrict__ dinv,
                                                   const int* __restrict__ rp, const int* __restrict__ srcl,
                                                   const float* __restrict__ bias, u16* __restrict__ out){
  const int i = blockIdx.x, t = threadIdx.x;
  const float di = dinv[i];
  bf16x4 hv = *(const bf16x4*)(H + (size_t)i*512 + t*4);
  float wself = di*di;
  float a0 = b2f((u16)hv[0])*wself, a1 = b2f((u16)hv[1])*wself, a2 = b2f((u16)hv[2])*wself, a3 = b2f((u16)hv[3])*wself;
  int e0 = rp[i], e1 = rp[i+1];
  for (int e=e0; e<e1; ++e){
    int s = srcl[e];
    float w = dinv[s]*di;
    bf16x4 v = *(const bf16x4*)(H + (size_t)s*512 + t*4);
    a0 += b2f((u16)v[0])*w; a1 += b2f((u16)v[1])*w; a2 += b2f((u16)v[2])*w; a3 += b2f((u16)v[3])*w;
  }
  a0 += bias[t*4+0]; a1 += bias[t*4+1]; a2 += bias[t*4+2]; a3 += bias[t*4+3];
  a0 = fmaxf(a0,0.f); a1 = fmaxf(a1,0.f); a2 = fmaxf(a2,0.f); a3 = fmaxf(a3,0.f);
  bf16x4 o; o[0]=(short)f2b(a0); o[1]=(short)f2b(a1); o[2]=(short)f2b(a2); o[3]=(short)f2b(a3);
  *(bf16x4*)(out + (size_t)i*512 + t*4) = o;
}

// ---------------- GEMM: C[M,N] = A[M,K] * B[N,K]^T (+bias, +resid, relu), bf16 in, bf16/f32 out ----------------
template<int BM,int BN,int WM,int WN,bool BIAS,bool RESID,bool RELU,bool OUTBF>
__global__ __launch_bounds__(256) void gemm_abt_k(
    const u16* __restrict__ A, const u16* __restrict__ B,
    const float* __restrict__ bias, const u16* __restrict__ resid,
    void* __restrict__ Cp, int M, int N, int K)
{
  constexpr int BK = 64;
  constexpr int AISS = (BM*BK)/(256*8);
  constexpr int BISS = (BN*BK)/(256*8);
  constexpr int WC = BN/WN;
  constexpr int FM = WM/16, FN = WN/16;
  __shared__ u16 As[BM*BK];
  __shared__ u16 Bs[BN*BK];
  const int tid = threadIdx.x;
  const int wv = tid>>6, ln = tid&63;
  const int l15 = ln&15, l4 = ln>>4;
  const int wm = wv / WC, wn = wv % WC;
  const int bm0 = blockIdx.x*BM, bn0 = blockIdx.y*BN;
  const int arow = tid>>3;          // row within a 32-row staging group
  const int acol = (tid&7)*8;       // element col within 64
  f32x4 acc[FM][FN];
  #pragma unroll
  for (int a=0;a<FM;++a)
    #pragma unroll
    for (int b=0;b<FN;++b) acc[a][b] = f32x4{0.f,0.f,0.f,0.f};
  bf16x8 ra[AISS], rb[BISS];
  #pragma unroll
  for (int i=0;i<AISS;++i) ra[i] = *(const bf16x8*)(A + (size_t)(bm0 + i*32 + arow)*K + acol);
  #pragma unroll
  for (int i=0;i<BISS;++i) rb[i] = *(const bf16x8*)(B + (size_t)(bn0 + i*32 + arow)*K + acol);
  for (int kt=0; kt<K; kt+=BK){
    #pragma unroll
    for (int i=0;i<AISS;++i) *(bf16x8*)(&As[i*2048 + tid*8]) = ra[i];
    #pragma unroll
    for (int i=0;i<BISS;++i) *(bf16x8*)(&Bs[i*2048 + tid*8]) = rb[i];
    __syncthreads();
    if (kt + BK < K){
      #pragma unroll
      for (int i=0;i<AISS;++i) ra[i] = *(const bf16x8*)(A + (size_t)(bm0 + i*32 + arow)*K + kt + BK + acol);
      #pragma unroll
      for (int i=0;i<BISS;++i) rb[i] = *(const bf16x8*)(B + (size_t)(bn0 + i*32 + arow)*K + kt + BK + acol);
    }
    #pragma unroll
    for (int kc=0;kc<2;++kc){
      bf16x8 af[FM], bfr[FN];
      #pragma unroll
      for (int a=0;a<FM;++a) af[a] = *(const bf16x8*)(&As[(wm*WM + a*16 + l15)*BK + kc*32 + l4*8]);
      #pragma unroll
      for (int b=0;b<FN;++b) bfr[b] = *(const bf16x8*)(&Bs[(wn*WN + b*16 + l15)*BK + kc*32 + l4*8]);
      #pragma unroll
      for (int a=0;a<FM;++a)
        #pragma unroll
        for (int b=0;b<FN;++b)
          acc[a][b] = __builtin_amdgcn_mfma_f32_16x16x32_bf16(af[a], bfr[b], acc[a][b], 0,0,0);
    }
    __syncthreads();
  }
  #pragma unroll
  for (int a=0;a<FM;++a)
    #pragma unroll
    for (int b=0;b<FN;++b){
      #pragma unroll
      for (int j=0;j<4;++j){
        int r = bm0 + wm*WM + a*16 + l4*4 + j;
        int c = bn0 + wn*WN + b*16 + l15;
        float v = acc[a][b][j];
        if (BIAS)  v += bias[c];
        if (RESID) v += b2f(resid[(size_t)r*N + c]);
        if (RELU)  v = fmaxf(v, 0.f);
        if (OUTBF) ((u16*)Cp)[(size_t)r*N + c] = f2b(v);
        else       ((float*)Cp)[(size_t)r*N + c] = v;
      }
    }
}

// ---------------- flash attention: 4 heads, DH=128, N=4096, qkv bf16 [4096][1536] ----------------
__global__ __launch_bounds__(256) void attn_k(const u16* __restrict__ qkv, u16* __restrict__ oatt){
  const int head = blockIdx.y;
  const int qb0 = blockIdx.x*64;
  __shared__ u16 Ks[64*128];   // XOR-swizzled row-major K tile
  __shared__ u16 Vt[128*64];   // XOR-swizzled transposed V tile
  __shared__ u16 Ps[4][16*64]; // per-wave P tile
  const int tid = threadIdx.x, wv = tid>>6, ln = tid&63;
  const int l15 = ln&15, l4 = ln>>4;
  bf16x8 qf[4];
  {
    const u16* qp = qkv + (size_t)(qb0 + wv*16 + l15)*1536 + head*128 + l4*8;
    #pragma unroll
    for (int c=0;c<4;++c) qf[c] = *(const bf16x8*)(qp + c*32);
  }
  float m_run[4] = {-1e30f,-1e30f,-1e30f,-1e30f};
  float l_run[4] = {0.f,0.f,0.f,0.f};
  f32x4 acc_o[8];
  #pragma unroll
  for (int g=0;g<8;++g) acc_o[g] = f32x4{0.f,0.f,0.f,0.f};
  const int krow = tid>>4;       // 0..15
  const int kcol = (tid&15)*8;   // element col (0..120)
  bf16x8 kreg[4], vreg[4];
  #pragma unroll
  for (int i=0;i<4;++i){
    kreg[i] = *(const bf16x8*)(qkv + (size_t)(i*16 + krow)*1536 + 512 + head*128 + kcol);
    vreg[i] = *(const bf16x8*)(qkv + (size_t)(ln)*1536 + 1024 + head*128 + wv*8 + i*32);
  }
  for (int kv0=0; kv0<4096; kv0+=64){
    // stage regs -> LDS (K swizzled, V transposed+swizzled)
    #pragma unroll
    for (int i=0;i<4;++i){
      int r = i*16 + krow;
      *(bf16x8*)((char*)Ks + r*256 + ((kcol*2) ^ ((r&7)<<4))) = kreg[i];
      int d0 = wv*8 + i*32;
      #pragma unroll
      for (int j=0;j<8;++j){
        int row = d0 + j;
        *(u16*)((char*)Vt + ((row*128 + ln*2) ^ ((row&7)<<4))) = (u16)vreg[i][j];
      }
    }
    __syncthreads();
    if (kv0 + 64 < 4096){
      int nb = kv0 + 64;
      #pragma unroll
      for (int i=0;i<4;++i){
        kreg[i] = *(const bf16x8*)(qkv + (size_t)(nb + i*16 + krow)*1536 + 512 + head*128 + kcol);
        vreg[i] = *(const bf16x8*)(qkv + (size_t)(nb + ln)*1536 + 1024 + head*128 + wv*8 + i*32);
      }
    }
    // S = Q K^T  (each wave: 16 q-rows x 64 k-cols)
    f32x4 sacc[4];
    #pragma unroll
    for (int c=0;c<4;++c) sacc[c] = f32x4{0.f,0.f,0.f,0.f};
    #pragma unroll
    for (int c=0;c<4;++c){
      int row = c*16 + l15;
      #pragma unroll
      for (int kc=0;kc<4;++kc){
        bf16x8 kf = *(const bf16x8*)((char*)Ks + row*256 + ((kc*64 + l4*16) ^ ((row&7)<<4)));
        sacc[c] = __builtin_amdgcn_mfma_f32_16x16x32_bf16(qf[kc], kf, sacc[c], 0,0,0);
      }
    }
    const float SC = 0.08838834764831845f;
    #pragma unroll
    for (int j=0;j<4;++j){
      sacc[0][j]*=SC; sacc[1][j]*=SC; sacc[2][j]*=SC; sacc[3][j]*=SC;
      float m = fmaxf(fmaxf(sacc[0][j],sacc[1][j]), fmaxf(sacc[2][j],sacc[3][j]));
      #pragma unroll
      for (int s=1;s<16;s<<=1) m = fmaxf(m, __shfl_xor(m, s, 64));
      float mN = fmaxf(m_run[j], m);
      float cr = __expf(m_run[j] - mN);
      m_run[j] = mN;
      float r = 0.f;
      #pragma unroll
      for (int c=0;c<4;++c){ float p = __expf(sacc[c][j] - mN); sacc[c][j] = p; r += p; }
      #pragma unroll
      for (int s=1;s<16;s<<=1) r += __shfl_xor(r, s, 64);
      #pragma unroll
      for (int g=0;g<8;++g) acc_o[g][j] *= cr;
      l_run[j] = l_run[j]*cr + r;
    }
    // P (bf16) -> per-wave LDS
    #pragma unroll
    for (int c=0;c<4;++c)
      #pragma unroll
      for (int j=0;j<4;++j){
        int row = l4*4 + j;
        *(u16*)((char*)&Ps[wv][0] + ((row*128 + (c*16+l15)*2) ^ ((row&7)<<4))) = f2b(sacc[c][j]);
      }
    // O += P V
    #pragma unroll
    for (int kc2=0;kc2<2;++kc2){
      bf16x8 pf = *(const bf16x8*)((char*)&Ps[wv][0] + l15*128 + ((kc2*64 + l4*16) ^ ((l15&7)<<4)));
      #pragma unroll
      for (int g=0;g<8;++g){
        int row = g*16 + l15;
        bf16x8 vf = *(const bf16x8*)((char*)Vt + row*128 + ((kc2*64 + l4*16) ^ ((row&7)<<4)));
        acc_o[g] = __builtin_amdgcn_mfma_f32_16x16x32_bf16(pf, vf, acc_o[g], 0,0,0);
      }
    }
    __syncthreads();
  }
  #pragma unroll
  for (int j=0;j<4;++j){
    float inv = 1.0f / l_run[j];
    int r = qb0 + wv*16 + l4*4 + j;
    #pragma unroll
    for (int g=0;g<8;++g){
      oatt[(size_t)r*512 + head*128 + g*16 + l15] = f2b(acc_o[g][j] * inv);
    }
  }
}

// ---------------- launch ----------------
extern "C" void kernel_launch(void* const* d_in, const int* in_sizes, int n_in,
                              void* d_out, int out_size, void* d_ws, size_t ws_size,
                              hipStream_t stream) {
  (void)n_in; (void)out_size; (void)ws_size;
  const float* x    = (const float*)d_in[0];
  const int*   ei   = (const int*)d_in[1];
  const float* W1   = (const float*)d_in[2];
  const float* b1   = (const float*)d_in[3];
  const float* inw  = (const float*)d_in[4];
  const float* inb  = (const float*)d_in[5];
  const float* outw = (const float*)d_in[6];
  const float* outb = (const float*)d_in[7];
  const float* W2   = (const float*)d_in[8];
  const float* b2   = (const float*)d_in[9];
  const float* Wc   = (const float*)d_in[10];
  const float* bc   = (const float*)d_in[11];
  float* out = (float*)d_out;
  const int E = in_sizes[1] / 2;
  const int* srcp = ei;
  const int* dstp = ei + E;

  char* base = (char*)d_ws;
  size_t off = 0;
  auto alloc = [&](size_t bytes)->void*{
    void* p = base + off;
    off = (off + bytes + 255) & ~((size_t)255);
    return p;
  };
  u16* Xb    = (u16*)alloc((size_t)4096*768*2);
  u16* W1T   = (u16*)alloc((size_t)512*768*2);
  u16* inWb  = (u16*)alloc((size_t)1536*512*2);
  u16* outWb = (u16*)alloc((size_t)512*512*2);
  u16* W2T   = (u16*)alloc((size_t)512*512*2);
  u16* WcT   = (u16*)alloc((size_t)32*512*2);
  u16* Hpre  = (u16*)alloc((size_t)4096*512*2);
  u16* h1    = (u16*)alloc((size_t)4096*512*2);
  u16* qkvb  = (u16*)alloc((size_t)4096*1536*2);
  u16* oatt  = (u16*)alloc((size_t)4096*512*2);
  u16* h2    = (u16*)alloc((size_t)4096*512*2);
  u16* h3    = (u16*)alloc((size_t)4096*512*2);
  int*   deg  = (int*)alloc(4096*4);
  float* dinv = (float*)alloc(4096*4);
  int*   rowp = (int*)alloc(4097*4);
  int*   curs = (int*)alloc(4096*4);
  int*   srcl = (int*)alloc((size_t)E*4);

  // conversions / transposes
  convert_bf16_k<<<3072,256,0,stream>>>(x, Xb, 4096*768);
  convert_bf16_k<<<768,256,0,stream>>>(inw, inWb, 1536*512);
  convert_bf16_k<<<256,256,0,stream>>>(outw, outWb, 512*512);
  transpose_f32_bf16_k<<<dim3(16,24),256,0,stream>>>(W1, W1T, 768, 512);
  transpose_f32_bf16_k<<<dim3(16,16),256,0,stream>>>(W2, W2T, 512, 512);
  transpose_f32_bf16_k<<<dim3(1,16),256,0,stream>>>(Wc, WcT, 512, 32);

  // degree + CSR
  deg_init_k<<<16,256,0,stream>>>(deg, 4096);
  deg_count_k<<<(E+255)/256,256,0,stream>>>(dstp, deg, E);
  scan_k<<<1,256,0,stream>>>(deg, rowp, curs, dinv);
  scatter_k<<<(E+255)/256,256,0,stream>>>(srcp, dstp, curs, srcl, E);

  // layer 1: x @ W1 -> aggregate -> relu
  gemm_abt_k<128,64,64,32,false,false,false,true><<<dim3(32,8),256,0,stream>>>(Xb, W1T, nullptr, nullptr, Hpre, 4096, 512, 768);
  aggregate_k<<<4096,128,0,stream>>>(Hpre, dinv, rowp, srcl, b1, h1);

  // MHA
  gemm_abt_k<128,64,64,32,true,false,false,true><<<dim3(32,24),256,0,stream>>>(h1, inWb, inb, nullptr, qkvb, 4096, 1536, 512);
  attn_k<<<dim3(64,4),256,0,stream>>>(qkvb, oatt);
  gemm_abt_k<128,64,64,32,true,true,false,true><<<dim3(32,8),256,0,stream>>>(oatt, outWb, outb, h1, h2, 4096, 512, 512);

  // layer 2: h2 @ W2 -> aggregate -> relu
  gemm_abt_k<128,64,64,32,false,false,false,true><<<dim3(32,8),256,0,stream>>>(h2, W2T, nullptr, nullptr, Hpre, 4096, 512, 512);
  aggregate_k<<<4096,128,0,stream>>>(Hpre, dinv, rowp, srcl, b2, h3);

  // classifier -> f32 out
  gemm_abt_k<64,32,16,32,true,false,false,false><<<dim3(64,1),256,0,stream>>>(h3, WcT, bc, nullptr, out, 4096, 32, 512);
}

// Round 2
// 186.004 us; speedup vs baseline: 1.4475x; 1.4475x over previous
//
#include <hip/hip_runtime.h>

typedef unsigned short u16;
typedef unsigned int u32;
typedef __attribute__((ext_vector_type(8))) short bf16x8;
typedef __attribute__((ext_vector_type(4))) short bf16x4;
typedef __attribute__((ext_vector_type(4))) float f32x4;
typedef __attribute__((ext_vector_type(16))) float f32x16;

__device__ __forceinline__ float b2f(u16 b){ u32 u = ((u32)b)<<16; float f; __builtin_memcpy(&f,&u,4); return f; }
__device__ __forceinline__ u16 f2b(float f){ u32 u; __builtin_memcpy(&u,&f,4); u32 r = (u + 0x7fffu + ((u>>16)&1u)) >> 16; return (u16)r; }
__device__ __forceinline__ u32 cvtpk(float lo, float hi){ u32 r; asm("v_cvt_pk_bf16_f32 %0, %1, %2" : "=v"(r) : "v"(lo), "v"(hi)); return r; }
__device__ __forceinline__ void pswap(u32 &a, u32 &b){ asm("v_permlane32_swap_b32 %0, %1" : "+v"(a), "+v"(b)); }

// ---------------- convert f32 -> bf16 ----------------
__global__ __launch_bounds__(256) void convert_bf16_k(const float* __restrict__ in, u16* __restrict__ out, int n){
  int i = (blockIdx.x*256 + threadIdx.x)*4;
  if (i + 3 < n){
    float4 v = *(const float4*)(in + i);
    bf16x4 o;
    o[0]=(short)f2b(v.x); o[1]=(short)f2b(v.y); o[2]=(short)f2b(v.z); o[3]=(short)f2b(v.w);
    *(bf16x4*)(out + i) = o;
  } else {
    for (; i<n; ++i) out[i]=f2b(in[i]);
  }
}

// ---------------- transpose f32 [R][C] -> bf16 [C][R] ----------------
__global__ __launch_bounds__(256) void transpose_f32_bf16_k(const float* __restrict__ in, u16* __restrict__ out, int R, int C){
  __shared__ float tile[32][33];
  int tx = threadIdx.x & 31, ty = threadIdx.x >> 5;
  int c0 = blockIdx.x*32, r0 = blockIdx.y*32;
  #pragma unroll
  for (int k=0;k<4;++k){
    int r = r0 + ty + k*8, c = c0 + tx;
    if (r < R && c < C) tile[ty+k*8][tx] = in[(size_t)r*C + c];
  }
  __syncthreads();
  #pragma unroll
  for (int k=0;k<4;++k){
    int c = c0 + ty + k*8, r = r0 + tx;
    if (r < R && c < C) out[(size_t)c*R + r] = f2b(tile[tx][ty+k*8]);
  }
}

// ---------------- degree / CSR ----------------
__global__ __launch_bounds__(256) void deg_init_k(int* __restrict__ deg, int n){
  int i = blockIdx.x*256 + threadIdx.x;
  if (i < n) deg[i] = 1;
}
__global__ __launch_bounds__(256) void deg_count_k(const int* __restrict__ dst, int* __restrict__ deg, int E){
  int e = blockIdx.x*256 + threadIdx.x;
  if (e < E) atomicAdd(&deg[dst[e]], 1);
}
__global__ __launch_bounds__(256) void scan_k(const int* __restrict__ deg, int* __restrict__ row_ptr,
                                              int* __restrict__ cursor, float* __restrict__ dinv){
  __shared__ int lds[256];
  int t = threadIdx.x;
  int base = t*16;
  int cnt[16]; int s = 0;
  #pragma unroll
  for (int k=0;k<16;++k){
    int d = deg[base+k];
    cnt[k] = d - 1;
    s += d - 1;
    dinv[base+k] = 1.0f / sqrtf((float)d);
  }
  lds[t] = s; __syncthreads();
  for (int o=1;o<256;o<<=1){
    int v = (t>=o) ? lds[t-o] : 0;
    __syncthreads();
    lds[t] += v;
    __syncthreads();
  }
  int run = lds[t] - s;
  #pragma unroll
  for (int k=0;k<16;++k){ row_ptr[base+k] = run; cursor[base+k] = run; run += cnt[k]; }
  if (t == 255) row_ptr[4096] = run;
}
__global__ __launch_bounds__(256) void scatter_k(const int* __restrict__ src, const int* __restrict__ dst,
                                                 int* __restrict__ cursor, int* __restrict__ srcl, int E){
  int e = blockIdx.x*256 + threadIdx.x;
  if (e < E){
    int d = dst[e];
    int pos = atomicAdd(&cursor[d], 1);
    srcl[pos] = src[e];
  }
}

// ---------------- GCN aggregation ----------------
__global__ __launch_bounds__(128) void aggregate_k(const u16* __restrict__ H, const float* __restrict__ dinv,
                                                   const int* __restrict__ rp, const int* __restrict__ srcl,
                                                   const float* __restrict__ bias, u16* __restrict__ out){
  const int i = blockIdx.x, t = threadIdx.x;
  const float di = dinv[i];
  bf16x4 hv = *(const bf16x4*)(H + (size_t)i*512 + t*4);
  float wself = di*di;
  float a0 = b2f((u16)hv[0])*wself, a1 = b2f((u16)hv[1])*wself, a2 = b2f((u16)hv[2])*wself, a3 = b2f((u16)hv[3])*wself;
  int e0 = rp[i], e1 = rp[i+1];
  for (int e=e0; e<e1; ++e){
    int s = srcl[e];
    float w = dinv[s]*di;
    bf16x4 v = *(const bf16x4*)(H + (size_t)s*512 + t*4);
    a0 += b2f((u16)v[0])*w; a1 += b2f((u16)v[1])*w; a2 += b2f((u16)v[2])*w; a3 += b2f((u16)v[3])*w;
  }
  a0 += bias[t*4+0]; a1 += bias[t*4+1]; a2 += bias[t*4+2]; a3 += bias[t*4+3];
  a0 = fmaxf(a0,0.f); a1 = fmaxf(a1,0.f); a2 = fmaxf(a2,0.f); a3 = fmaxf(a3,0.f);
  bf16x4 o; o[0]=(short)f2b(a0); o[1]=(short)f2b(a1); o[2]=(short)f2b(a2); o[3]=(short)f2b(a3);
  *(bf16x4*)(out + (size_t)i*512 + t*4) = o;
}

// ---------------- GEMM: C[M,N] = A[M,K] * B[N,K]^T ----------------
// QKV mode: N=1536; cols<512 scaled by QS -> qkvb, 512..1023 -> qkvb, >=1024 -> vt transposed [512][4096]
template<int BM,int BN,int WM,int WN,bool BIAS,bool RESID,bool RELU,bool OUTBF,bool QKV>
__global__ __launch_bounds__(256) void gemm_abt_k(
    const u16* __restrict__ A, const u16* __restrict__ B,
    const float* __restrict__ bias, const u16* __restrict__ resid,
    u16* __restrict__ vt, void* __restrict__ Cp, int M, int N, int K)
{
  constexpr int BK = 64;
  constexpr int AISS = (BM*BK)/(256*8);
  constexpr int BISS = (BN*BK)/(256*8);
  constexpr int WC = BN/WN;
  constexpr int FM = WM/16, FN = WN/16;
  constexpr float QS = 0.08838834764831845f;
  __shared__ u16 As[BM*BK];
  __shared__ u16 Bs[BN*BK];
  const int tid = threadIdx.x;
  const int wv = tid>>6, ln = tid&63;
  const int l15 = ln&15, l4 = ln>>4;
  const int wm = wv / WC, wn = wv % WC;
  const int bm0 = blockIdx.x*BM, bn0 = blockIdx.y*BN;
  const int arow = tid>>3;
  const int acol = (tid&7)*8;
  f32x4 acc[FM][FN];
  #pragma unroll
  for (int a=0;a<FM;++a)
    #pragma unroll
    for (int b=0;b<FN;++b) acc[a][b] = f32x4{0.f,0.f,0.f,0.f};
  bf16x8 ra[AISS], rb[BISS];
  #pragma unroll
  for (int i=0;i<AISS;++i) ra[i] = *(const bf16x8*)(A + (size_t)(bm0 + i*32 + arow)*K + acol);
  #pragma unroll
  for (int i=0;i<BISS;++i) rb[i] = *(const bf16x8*)(B + (size_t)(bn0 + i*32 + arow)*K + acol);
  for (int kt=0; kt<K; kt+=BK){
    #pragma unroll
    for (int i=0;i<AISS;++i) *(bf16x8*)(&As[i*2048 + tid*8]) = ra[i];
    #pragma unroll
    for (int i=0;i<BISS;++i) *(bf16x8*)(&Bs[i*2048 + tid*8]) = rb[i];
    __syncthreads();
    if (kt + BK < K){
      #pragma unroll
      for (int i=0;i<AISS;++i) ra[i] = *(const bf16x8*)(A + (size_t)(bm0 + i*32 + arow)*K + kt + BK + acol);
      #pragma unroll
      for (int i=0;i<BISS;++i) rb[i] = *(const bf16x8*)(B + (size_t)(bn0 + i*32 + arow)*K + kt + BK + acol);
    }
    #pragma unroll
    for (int kc=0;kc<2;++kc){
      bf16x8 af[FM], bfr[FN];
      #pragma unroll
      for (int a=0;a<FM;++a) af[a] = *(const bf16x8*)(&As[(wm*WM + a*16 + l15)*BK + kc*32 + l4*8]);
      #pragma unroll
      for (int b=0;b<FN;++b) bfr[b] = *(const bf16x8*)(&Bs[(wn*WN + b*16 + l15)*BK + kc*32 + l4*8]);
      #pragma unroll
      for (int a=0;a<FM;++a)
        #pragma unroll
        for (int b=0;b<FN;++b)
          acc[a][b] = __builtin_amdgcn_mfma_f32_16x16x32_bf16(af[a], bfr[b], acc[a][b], 0,0,0);
    }
    __syncthreads();
  }
  #pragma unroll
  for (int a=0;a<FM;++a)
    #pragma unroll
    for (int b=0;b<FN;++b){
      int r0 = bm0 + wm*WM + a*16 + l4*4;
      int c  = bn0 + wn*WN + b*16 + l15;
      if constexpr (QKV){
        float v0 = acc[a][b][0] + bias[c];
        float v1 = acc[a][b][1] + bias[c];
        float v2 = acc[a][b][2] + bias[c];
        float v3 = acc[a][b][3] + bias[c];
        if (c >= 1024){
          bf16x4 pk; pk[0]=(short)f2b(v0); pk[1]=(short)f2b(v1); pk[2]=(short)f2b(v2); pk[3]=(short)f2b(v3);
          *(bf16x4*)(vt + (size_t)(c-1024)*4096 + r0) = pk;
        } else {
          float s = (c < 512) ? QS : 1.0f;
          u16* o = (u16*)Cp;
          o[(size_t)(r0+0)*N + c] = f2b(v0*s);
          o[(size_t)(r0+1)*N + c] = f2b(v1*s);
          o[(size_t)(r0+2)*N + c] = f2b(v2*s);
          o[(size_t)(r0+3)*N + c] = f2b(v3*s);
        }
      } else {
        #pragma unroll
        for (int j=0;j<4;++j){
          int r = r0 + j;
          float v = acc[a][b][j];
          if (BIAS)  v += bias[c];
          if (RESID) v += b2f(resid[(size_t)r*N + c]);
          if (RELU)  v = fmaxf(v, 0.f);
          if (OUTBF) ((u16*)Cp)[(size_t)r*N + c] = f2b(v);
          else       ((float*)Cp)[(size_t)r*N + c] = v;
        }
      }
    }
}

// ---------------- flash attention v2: 32x32 MFMA, swapped QK^T, no-max softmax, KV-split partials ----------------
// grid (32 qtiles, 4 heads, 4 splits), 256 threads (4 waves x 32 q-rows)
__global__ __launch_bounds__(256,2) void attn_k(const u16* __restrict__ qkv, const u16* __restrict__ vtg,
                                                float* __restrict__ Op, float* __restrict__ Lp){
  __shared__ u16 Ks[64*128];    // 64 kv rows x 256B (16 granules), XOR-swz (row&15)
  __shared__ u16 Vs[128*128];   // 128 d rows x 256B (8 data granules), XOR-swz (row&15)
  const int head = blockIdx.y, split = blockIdx.z;
  const int qb0 = blockIdx.x*128;
  const int tid = threadIdx.x, wv = tid>>6, ln = tid&63;
  const int l31 = ln&31, hi = ln>>5;
  bf16x8 qf[8];
  {
    const u16* qp = qkv + (size_t)(qb0 + wv*32 + l31)*1536 + head*128 + hi*8;
    #pragma unroll
    for (int kk=0;kk<8;++kk) qf[kk] = *(const bf16x8*)(qp + kk*16);
  }
  f32x16 acc_o[4];
  #pragma unroll
  for (int d=0;d<4;++d)
    #pragma unroll
    for (int r=0;r<16;++r) acc_o[d][r] = 0.f;
  float l_part = 0.f;
  const int kR = ln, kG = wv*4;           // K stage: row=lane, 4 granules per thread
  const int vR = tid>>1, vG = (tid&1)*4;  // V stage: row=d, 4 granules per thread
  const u16* kbase = qkv + 512 + (size_t)head*128;
  const u16* vbase = vtg + (size_t)(head*128 + vR)*4096;
  const int kv00 = split*1024;
  bf16x8 kreg[4], vreg[4];
  #pragma unroll
  for (int i=0;i<4;++i){
    kreg[i] = *(const bf16x8*)(kbase + (size_t)(kv00 + kR)*1536 + (kG+i)*8);
    vreg[i] = *(const bf16x8*)(vbase + kv00 + (vG+i)*8);
  }
  for (int it=0; it<16; ++it){
    #pragma unroll
    for (int i=0;i<4;++i){
      *(bf16x8*)((char*)Ks + kR*256 + (((kG+i)*16) ^ ((kR&15)<<4))) = kreg[i];
      *(bf16x8*)((char*)Vs + vR*256 + (((vG+i)*16) ^ ((vR&15)<<4))) = vreg[i];
    }
    __syncthreads();
    if (it < 15){
      int nb = kv00 + (it+1)*64;
      #pragma unroll
      for (int i=0;i<4;++i){
        kreg[i] = *(const bf16x8*)(kbase + (size_t)(nb + kR)*1536 + (kG+i)*8);
        vreg[i] = *(const bf16x8*)(vbase + nb + (vG+i)*8);
      }
    }
    // swapped QK^T: S[kv][q], a=K-frag (LDS), b=Q-frag (regs)
    f32x16 s0, s1;
    #pragma unroll
    for (int r=0;r<16;++r){ s0[r]=0.f; s1[r]=0.f; }
    #pragma unroll
    for (int kk=0;kk<8;++kk){
      int r0 = l31, r1 = 32 + l31;
      bf16x8 k0 = *(const bf16x8*)((char*)Ks + r0*256 + ((kk*32 + hi*16) ^ ((r0&15)<<4)));
      bf16x8 k1 = *(const bf16x8*)((char*)Ks + r1*256 + ((kk*32 + hi*16) ^ ((r1&15)<<4)));
      s0 = __builtin_amdgcn_mfma_f32_32x32x16_bf16(k0, qf[kk], s0, 0,0,0);
      s1 = __builtin_amdgcn_mfma_f32_32x32x16_bf16(k1, qf[kk], s1, 0,0,0);
    }
    // p = exp(s) (Q pre-scaled; shift-free softmax), pack to PV A-frags in-register
    union PU { u32 w[4]; bf16x8 v; };
    PU pa[4];
    #pragma unroll
    for (int g=0; g<2; ++g){
      float p[16];
      #pragma unroll
      for (int r=0;r<16;++r){ float sv = g ? s1[r] : s0[r]; p[r] = __expf(sv); l_part += p[r]; }
      u32 c0=cvtpk(p[0],p[1]), c1=cvtpk(p[2],p[3]), c2=cvtpk(p[4],p[5]), c3=cvtpk(p[6],p[7]);
      u32 c4=cvtpk(p[8],p[9]), c5=cvtpk(p[10],p[11]), c6=cvtpk(p[12],p[13]), c7=cvtpk(p[14],p[15]);
      pswap(c0,c2); pswap(c1,c3); pswap(c4,c6); pswap(c5,c7);
      pa[g*2+0].w[0]=c0; pa[g*2+0].w[1]=c1; pa[g*2+0].w[2]=c2; pa[g*2+0].w[3]=c3;
      pa[g*2+1].w[0]=c4; pa[g*2+1].w[1]=c5; pa[g*2+1].w[2]=c6; pa[g*2+1].w[3]=c7;
    }
    // O += P V  (a = P-frag regs, b = V^T-frag LDS)
    #pragma unroll
    for (int dg=0;dg<4;++dg){
      int row = dg*32 + l31;
      #pragma unroll
      for (int kvf=0;kvf<4;++kvf){
        bf16x8 vf = *(const bf16x8*)((char*)Vs + row*256 + ((kvf*32 + hi*16) ^ ((row&15)<<4)));
        acc_o[dg] = __builtin_amdgcn_mfma_f32_32x32x16_bf16(pa[kvf].v, vf, acc_o[dg], 0,0,0);
      }
    }
    __syncthreads();
  }
  float l_tot = l_part + __shfl_xor(l_part, 32, 64);
  if (hi == 0) Lp[split*4096 + qb0 + wv*32 + l31] = l_tot;
  #pragma unroll
  for (int dg=0;dg<4;++dg){
    #pragma unroll
    for (int r=0;r<16;++r){
      int q = qb0 + wv*32 + (r&3) + ((r>>2)<<3) + hi*4;
      Op[((size_t)split*4096 + q)*512 + head*128 + dg*32 + l31] = acc_o[dg][r];
    }
  }
}

// ---------------- combine partials -> oatt bf16 ----------------
__global__ __launch_bounds__(256) void combine_k(const float* __restrict__ Op, const float* __restrict__ Lp,
                                                 u16* __restrict__ oatt){
  int idx = blockIdx.x*256 + threadIdx.x;   // 4096*64
  int n = idx >> 6, c8 = (idx & 63) << 3;
  float l = Lp[n] + Lp[4096+n] + Lp[8192+n] + Lp[12288+n];
  float inv = 1.0f/l;
  float acc[8] = {0,0,0,0,0,0,0,0};
  #pragma unroll
  for (int s=0;s<4;++s){
    const float* p = Op + ((size_t)(s*4096+n))*512 + c8;
    float4 u = *(const float4*)p;
    float4 v = *(const float4*)(p+4);
    acc[0]+=u.x; acc[1]+=u.y; acc[2]+=u.z; acc[3]+=u.w;
    acc[4]+=v.x; acc[5]+=v.y; acc[6]+=v.z; acc[7]+=v.w;
  }
  bf16x8 o;
  #pragma unroll
  for (int j=0;j<8;++j) o[j] = (short)f2b(acc[j]*inv);
  *(bf16x8*)(oatt + (size_t)n*512 + c8) = o;
}

// ---------------- launch ----------------
extern "C" void kernel_launch(void* const* d_in, const int* in_sizes, int n_in,
                              void* d_out, int out_size, void* d_ws, size_t ws_size,
                              hipStream_t stream) {
  (void)n_in; (void)out_size; (void)ws_size;
  const float* x    = (const float*)d_in[0];
  const int*   ei   = (const int*)d_in[1];
  const float* W1   = (const float*)d_in[2];
  const float* b1   = (const float*)d_in[3];
  const float* inw  = (const float*)d_in[4];
  const float* inb  = (const float*)d_in[5];
  const float* outw = (const float*)d_in[6];
  const float* outb = (const float*)d_in[7];
  const float* W2   = (const float*)d_in[8];
  const float* b2   = (const float*)d_in[9];
  const float* Wc   = (const float*)d_in[10];
  const float* bc   = (const float*)d_in[11];
  float* out = (float*)d_out;
  const int E = in_sizes[1] / 2;
  const int* srcp = ei;
  const int* dstp = ei + E;

  char* base = (char*)d_ws;
  size_t off = 0;
  auto alloc = [&](size_t bytes)->void*{
    void* p = base + off;
    off = (off + bytes + 255) & ~((size_t)255);
    return p;
  };
  u16* Xb    = (u16*)alloc((size_t)4096*768*2);
  u16* W1T   = (u16*)alloc((size_t)512*768*2);
  u16* inWb  = (u16*)alloc((size_t)1536*512*2);
  u16* outWb = (u16*)alloc((size_t)512*512*2);
  u16* W2T   = (u16*)alloc((size_t)512*512*2);
  u16* WcT   = (u16*)alloc((size_t)32*512*2);
  u16* Hpre  = (u16*)alloc((size_t)4096*512*2);
  u16* h1    = (u16*)alloc((size_t)4096*512*2);
  u16* qkvb  = (u16*)alloc((size_t)4096*1536*2);
  u16* vtg   = (u16*)alloc((size_t)512*4096*2);
  u16* oatt  = (u16*)alloc((size_t)4096*512*2);
  u16* h2    = (u16*)alloc((size_t)4096*512*2);
  u16* h3    = (u16*)alloc((size_t)4096*512*2);
  float* Opart = (float*)alloc((size_t)4*4096*512*4);
  float* Lpart = (float*)alloc((size_t)4*4096*4);
  int*   deg  = (int*)alloc(4096*4);
  float* dinv = (float*)alloc(4096*4);
  int*   rowp = (int*)alloc(4097*4);
  int*   curs = (int*)alloc(4096*4);
  int*   srcl = (int*)alloc((size_t)E*4);

  // conversions / transposes
  convert_bf16_k<<<3072,256,0,stream>>>(x, Xb, 4096*768);
  convert_bf16_k<<<768,256,0,stream>>>(inw, inWb, 1536*512);
  convert_bf16_k<<<256,256,0,stream>>>(outw, outWb, 512*512);
  transpose_f32_bf16_k<<<dim3(16,24),256,0,stream>>>(W1, W1T, 768, 512);
  transpose_f32_bf16_k<<<dim3(16,16),256,0,stream>>>(W2, W2T, 512, 512);
  transpose_f32_bf16_k<<<dim3(1,16),256,0,stream>>>(Wc, WcT, 512, 32);

  // degree + CSR
  deg_init_k<<<16,256,0,stream>>>(deg, 4096);
  deg_count_k<<<(E+255)/256,256,0,stream>>>(dstp, deg, E);
  scan_k<<<1,256,0,stream>>>(deg, rowp, curs, dinv);
  scatter_k<<<(E+255)/256,256,0,stream>>>(srcp, dstp, curs, srcl, E);

  // layer 1
  gemm_abt_k<128,64,64,32,false,false,false,true,false><<<dim3(32,8),256,0,stream>>>(Xb, W1T, nullptr, nullptr, nullptr, Hpre, 4096, 512, 768);
  aggregate_k<<<4096,128,0,stream>>>(Hpre, dinv, rowp, srcl, b1, h1);

  // MHA: qkv (q scaled, v transposed to vtg), flash attention, combine, out-proj(+resid)
  gemm_abt_k<128,64,64,32,true,false,false,true,true><<<dim3(32,24),256,0,stream>>>(h1, inWb, inb, nullptr, vtg, qkvb, 4096, 1536, 512);
  attn_k<<<dim3(32,4,4),256,0,stream>>>(qkvb, vtg, Opart, Lpart);
  combine_k<<<1024,256,0,stream>>>(Opart, Lpart, oatt);
  gemm_abt_k<128,64,64,32,true,true,false,true,false><<<dim3(32,8),256,0,stream>>>(oatt, outWb, outb, h1, nullptr, h2, 4096, 512, 512);

  // layer 2
  gemm_abt_k<128,64,64,32,false,false,false,true,false><<<dim3(32,8),256,0,stream>>>(h2, W2T, nullptr, nullptr, nullptr, Hpre, 4096, 512, 512);
  aggregate_k<<<4096,128,0,stream>>>(Hpre, dinv, rowp, srcl, b2, h3);

  // classifier -> f32 out
  gemm_abt_k<64,32,16,32,true,false,false,false,false><<<dim3(64,1),256,0,stream>>>(h3, WcT, bc, nullptr, nullptr, out, 4096, 32, 512);
}